// Round 9
// baseline (336.638 us; speedup 1.0000x reference)
//
#include <hip/hip_runtime.h>

// LogitSelector: per-row top-100 (ascending), label position, miss→replace col 0.
// Reference: jax.lax.top_k (ties: lower index first), reversed; take_along_axis; argmax.
//
// R8 (= R7 with compile fix: __builtin_nontemporal_load needs a NATIVE vector
// type, not HIP_vector_type float4). Attack the stuck ~75us streaming-read
// phase (R4/R5/R6 invariant):
//   - 16B nontemporal loads (ext_vector_type(4)); rows alternate 16B/8B
//     alignment (stride 26856 % 16 == 8) -> head/tail float2 by row parity.
//   - one LDS atomicAdd per float4 (was per element), branchy scalar stores.
// Rank phase unchanged from R6 (32-bit keys + readlane, tie slow path).

#define NROWS 8192
#define NCOLS 6714
#define NQ    1678     // 16B-quads per row (6712 elements); +1 float2 head/tail
#define K     100
#define CAP   512
#define BLK   256

typedef float f32x4 __attribute__((ext_vector_type(4)));
typedef float f32x2 __attribute__((ext_vector_type(2)));

__device__ __forceinline__ unsigned int flip32(float v) {
    unsigned int b = __float_as_uint(v);
    return ((int)b < 0) ? ~b : (b | 0x80000000u);   // order-preserving
}
__device__ __forceinline__ float unflip32(unsigned int k) {
    return __uint_as_float((k & 0x80000000u) ? (k ^ 0x80000000u) : ~k);
}

__global__ __launch_bounds__(BLK) void logit_selector_kernel(
    const float* __restrict__ out_mat,
    const int*   __restrict__ labels,
    float*       __restrict__ new_out,   // [NROWS][K]
    float*       __restrict__ new_lab)   // [NROWS] written as float
{
    __shared__ unsigned int cvkey[CAP];   // 2 KB
    __shared__ unsigned int cidx[CAP];    // 2 KB
    __shared__ unsigned int s_cnum;
    __shared__ int s_lab, s_has, s_dup;

    const int row  = blockIdx.x;
    const int tid  = threadIdx.x;
    const int lane = tid & 63;
    const float* __restrict__ rp = out_mat + (size_t)row * NCOLS;

    // row*NCOLS % 4 == 2 for odd rows -> their base is only 8B-aligned.
    const int ofs  = (row & 1) ? 2 : 0;           // 16B region = [ofs, ofs+6712)
    const int eofs = ofs ? 0 : 6712;              // leftover float2 = [eofs, eofs+2)
    const f32x4* __restrict__ p4 = (const f32x4*)(rp + ofs);

    if (tid == 0) { s_has = 0; s_lab = 0; s_dup = 0; }

    // --- Candidate collection: speculative threshold (retry ladder + bisection).
    float lo = -400.0f, hi = 400.0f, t = 2.1f;
    unsigned int cnt;
    for (int attempt = 0; ; ++attempt) {
        if (tid == 0) s_cnum = 0;
        __syncthreads();

        for (int i = tid; i < NQ; i += BLK) {
            const f32x4 q = __builtin_nontemporal_load(&p4[i]);
            const bool b0 = q.x > t, b1 = q.y > t, b2 = q.z > t, b3 = q.w > t;
            const int  m  = (int)b0 + (int)b1 + (int)b2 + (int)b3;
            if (m) {
                unsigned int pos = atomicAdd(&s_cnum, (unsigned int)m);
                const int e = ofs + 4 * i;
                if (b0) { if (pos < CAP) { cvkey[pos] = flip32(q.x); cidx[pos] = e;     } ++pos; }
                if (b1) { if (pos < CAP) { cvkey[pos] = flip32(q.y); cidx[pos] = e + 1; } ++pos; }
                if (b2) { if (pos < CAP) { cvkey[pos] = flip32(q.z); cidx[pos] = e + 2; } ++pos; }
                if (b3) { if (pos < CAP) { cvkey[pos] = flip32(q.w); cidx[pos] = e + 3; } ++pos; }
            }
        }
        if (tid == BLK - 1) {                      // leftover 2 elements
            const f32x2 qt = *(const f32x2*)(rp + eofs);
            if (qt.x > t) {
                unsigned int p = atomicAdd(&s_cnum, 1u);
                if (p < CAP) { cvkey[p] = flip32(qt.x); cidx[p] = eofs; }
            }
            if (qt.y > t) {
                unsigned int p = atomicAdd(&s_cnum, 1u);
                if (p < CAP) { cvkey[p] = flip32(qt.y); cidx[p] = eofs + 1; }
            }
        }
        __syncthreads();
        cnt = s_cnum;                        // uniform across block
        if ((cnt >= K && cnt <= CAP) || attempt >= 62) break;
        if (cnt < (unsigned int)K) hi = t; else lo = t;
        t = (attempt == 0) ? ((cnt < (unsigned int)K) ? 1.85f : 2.35f)
                           : 0.5f * (lo + hi);
        __syncthreads();                     // protect next reset vs. cnt reads
    }

    const int C    = (int)min(cnt, (unsigned int)CAP);
    const int Cpad = (C + 63) & ~63;
    for (int c = C + tid; c < Cpad; c += BLK) { cvkey[c] = 0u; cidx[c] = 0xFFFFFFFFu; }
    __syncthreads();

    const int label = labels[row];

    // --- Fast rank: 32-bit value keys; detect exact fp32 ties for slow path.
    // rank(j) = #{c: key_c > key_j}; distinct keys -> bijection onto [0,C).
    // rank k < K -> column (K-1)-k (reference reverses top_k order).
    for (int jbase = 0; jbase < C; jbase += BLK) {
        const int  j      = jbase + tid;
        const bool active = (j < C);
        if (__ballot(active) == 0) continue;          // whole wave idle
        unsigned int kj = 0;
        if (active) kj = cvkey[j];
        int rank = 0, eqc = 0;
        for (int cb = 0; cb < Cpad; cb += 64) {
            const unsigned int kt = cvkey[cb + lane];  // all lanes execute
            #pragma unroll
            for (int l = 0; l < 64; ++l) {
                const unsigned int kc = __builtin_amdgcn_readlane(kt, l);
                rank += (kc > kj);
                eqc  += (kc == kj);                    // includes self once
            }
        }
        if (active) {
            if (eqc >= 2) s_dup = 1;                   // exact value tie in row
            if (rank < K) {
                const int col = (K - 1) - rank;
                new_out[(size_t)row * K + col] = unflip32(kj);
                if ((int)cidx[j] == label) { s_has = 1; s_lab = col; }
            }
        }
    }
    __syncthreads();

    // --- Slow path (rare): exact (value desc, index asc) with 64-bit compare.
    if (s_dup) {
        if (tid == 0) { s_has = 0; s_lab = 0; }
        __syncthreads();
        for (int jbase = 0; jbase < C; jbase += BLK) {
            const int  j      = jbase + tid;
            const bool active = (j < C);
            if (__ballot(active) == 0) continue;
            unsigned int kj = 0, ijx = 0xFFFFFFFFu;
            if (active) { kj = cvkey[j]; ijx = cidx[j]; }
            int rank = 0;
            for (int cb = 0; cb < Cpad; cb += 64) {
                const unsigned int kt = cvkey[cb + lane];
                const unsigned int it = cidx[cb + lane];
                #pragma unroll
                for (int l = 0; l < 64; ++l) {
                    const unsigned int kc = __builtin_amdgcn_readlane(kt, l);
                    const unsigned int ic = __builtin_amdgcn_readlane(it, l);
                    rank += (kc > kj) || (kc == kj && ic < ijx);
                }
            }
            if (active && rank < K) {                  // bijective: all K written
                const int col = (K - 1) - rank;
                new_out[(size_t)row * K + col] = unflip32(kj);
                if ((int)cidx[j] == label) { s_has = 1; s_lab = col; }
            }
        }
        __syncthreads();
    }

    if (tid == 0) {
        int lab = s_lab;
        if (!s_has) {                        // label missed top-K: replace col 0
            new_out[(size_t)row * K] = rp[label];
            lab = 0;
        }
        new_lab[row] = (float)lab;
    }
}

extern "C" void kernel_launch(void* const* d_in, const int* in_sizes, int n_in,
                              void* d_out, int out_size, void* d_ws, size_t ws_size,
                              hipStream_t stream) {
    const float* out_mat = (const float*)d_in[0];
    const int*   labels  = (const int*)d_in[1];
    float* new_out = (float*)d_out;                      // 8192*100 floats
    float* new_lab = (float*)d_out + (size_t)NROWS * K;  // 8192 floats

    logit_selector_kernel<<<dim3(NROWS), dim3(BLK), 0, stream>>>(
        out_mat, labels, new_out, new_lab);
}

// Round 10
// 325.697 us; speedup vs baseline: 1.0336x; 1.0336x over previous
//
#include <hip/hip_runtime.h>

// LogitSelector: per-row top-100 (ascending), label position, miss→replace col 0.
// Reference: jax.lax.top_k (ties: lower index first), reversed; take_along_axis; argmax.
//
// R10 = R9 minus the nontemporal flag (one-variable revert). R9's nt loads
// bypassed L2/L3 allocation and forced the restore-cached half of the input
// (only ~106 of 220 MB comes from HBM per R5 FETCH_SIZE) out to HBM at the
// ~3 TB/s read-path ceiling -> +30us regression. Plain 16B loads keep cache
// hits; width itself is byte-neutral but halves vmem instruction count.
// Rank phase unchanged from R6 (32-bit keys + readlane, tie slow path).

#define NROWS 8192
#define NCOLS 6714
#define NQ    1678     // 16B-quads per row (6712 elements); +1 float2 head/tail
#define K     100
#define CAP   512
#define BLK   256

typedef float f32x4 __attribute__((ext_vector_type(4)));
typedef float f32x2 __attribute__((ext_vector_type(2)));

__device__ __forceinline__ unsigned int flip32(float v) {
    unsigned int b = __float_as_uint(v);
    return ((int)b < 0) ? ~b : (b | 0x80000000u);   // order-preserving
}
__device__ __forceinline__ float unflip32(unsigned int k) {
    return __uint_as_float((k & 0x80000000u) ? (k ^ 0x80000000u) : ~k);
}

__global__ __launch_bounds__(BLK) void logit_selector_kernel(
    const float* __restrict__ out_mat,
    const int*   __restrict__ labels,
    float*       __restrict__ new_out,   // [NROWS][K]
    float*       __restrict__ new_lab)   // [NROWS] written as float
{
    __shared__ unsigned int cvkey[CAP];   // 2 KB
    __shared__ unsigned int cidx[CAP];    // 2 KB
    __shared__ unsigned int s_cnum;
    __shared__ int s_lab, s_has, s_dup;

    const int row  = blockIdx.x;
    const int tid  = threadIdx.x;
    const int lane = tid & 63;
    const float* __restrict__ rp = out_mat + (size_t)row * NCOLS;

    // row*NCOLS % 4 == 2 for odd rows -> their base is only 8B-aligned.
    const int ofs  = (row & 1) ? 2 : 0;           // 16B region = [ofs, ofs+6712)
    const int eofs = ofs ? 0 : 6712;              // leftover float2 = [eofs, eofs+2)
    const f32x4* __restrict__ p4 = (const f32x4*)(rp + ofs);

    if (tid == 0) { s_has = 0; s_lab = 0; s_dup = 0; }

    // --- Candidate collection: speculative threshold (retry ladder + bisection).
    float lo = -400.0f, hi = 400.0f, t = 2.1f;
    unsigned int cnt;
    for (int attempt = 0; ; ++attempt) {
        if (tid == 0) s_cnum = 0;
        __syncthreads();

        for (int i = tid; i < NQ; i += BLK) {
            const f32x4 q = p4[i];
            const bool b0 = q.x > t, b1 = q.y > t, b2 = q.z > t, b3 = q.w > t;
            const int  m  = (int)b0 + (int)b1 + (int)b2 + (int)b3;
            if (m) {
                unsigned int pos = atomicAdd(&s_cnum, (unsigned int)m);
                const int e = ofs + 4 * i;
                if (b0) { if (pos < CAP) { cvkey[pos] = flip32(q.x); cidx[pos] = e;     } ++pos; }
                if (b1) { if (pos < CAP) { cvkey[pos] = flip32(q.y); cidx[pos] = e + 1; } ++pos; }
                if (b2) { if (pos < CAP) { cvkey[pos] = flip32(q.z); cidx[pos] = e + 2; } ++pos; }
                if (b3) { if (pos < CAP) { cvkey[pos] = flip32(q.w); cidx[pos] = e + 3; } ++pos; }
            }
        }
        if (tid == BLK - 1) {                      // leftover 2 elements
            const f32x2 qt = *(const f32x2*)(rp + eofs);
            if (qt.x > t) {
                unsigned int p = atomicAdd(&s_cnum, 1u);
                if (p < CAP) { cvkey[p] = flip32(qt.x); cidx[p] = eofs; }
            }
            if (qt.y > t) {
                unsigned int p = atomicAdd(&s_cnum, 1u);
                if (p < CAP) { cvkey[p] = flip32(qt.y); cidx[p] = eofs + 1; }
            }
        }
        __syncthreads();
        cnt = s_cnum;                        // uniform across block
        if ((cnt >= K && cnt <= CAP) || attempt >= 62) break;
        if (cnt < (unsigned int)K) hi = t; else lo = t;
        t = (attempt == 0) ? ((cnt < (unsigned int)K) ? 1.85f : 2.35f)
                           : 0.5f * (lo + hi);
        __syncthreads();                     // protect next reset vs. cnt reads
    }

    const int C    = (int)min(cnt, (unsigned int)CAP);
    const int Cpad = (C + 63) & ~63;
    for (int c = C + tid; c < Cpad; c += BLK) { cvkey[c] = 0u; cidx[c] = 0xFFFFFFFFu; }
    __syncthreads();

    const int label = labels[row];

    // --- Fast rank: 32-bit value keys; detect exact fp32 ties for slow path.
    // rank(j) = #{c: key_c > key_j}; distinct keys -> bijection onto [0,C).
    // rank k < K -> column (K-1)-k (reference reverses top_k order).
    for (int jbase = 0; jbase < C; jbase += BLK) {
        const int  j      = jbase + tid;
        const bool active = (j < C);
        if (__ballot(active) == 0) continue;          // whole wave idle
        unsigned int kj = 0;
        if (active) kj = cvkey[j];
        int rank = 0, eqc = 0;
        for (int cb = 0; cb < Cpad; cb += 64) {
            const unsigned int kt = cvkey[cb + lane];  // all lanes execute
            #pragma unroll
            for (int l = 0; l < 64; ++l) {
                const unsigned int kc = __builtin_amdgcn_readlane(kt, l);
                rank += (kc > kj);
                eqc  += (kc == kj);                    // includes self once
            }
        }
        if (active) {
            if (eqc >= 2) s_dup = 1;                   // exact value tie in row
            if (rank < K) {
                const int col = (K - 1) - rank;
                new_out[(size_t)row * K + col] = unflip32(kj);
                if ((int)cidx[j] == label) { s_has = 1; s_lab = col; }
            }
        }
    }
    __syncthreads();

    // --- Slow path (rare): exact (value desc, index asc) with 64-bit compare.
    if (s_dup) {
        if (tid == 0) { s_has = 0; s_lab = 0; }
        __syncthreads();
        for (int jbase = 0; jbase < C; jbase += BLK) {
            const int  j      = jbase + tid;
            const bool active = (j < C);
            if (__ballot(active) == 0) continue;
            unsigned int kj = 0, ijx = 0xFFFFFFFFu;
            if (active) { kj = cvkey[j]; ijx = cidx[j]; }
            int rank = 0;
            for (int cb = 0; cb < Cpad; cb += 64) {
                const unsigned int kt = cvkey[cb + lane];
                const unsigned int it = cidx[cb + lane];
                #pragma unroll
                for (int l = 0; l < 64; ++l) {
                    const unsigned int kc = __builtin_amdgcn_readlane(kt, l);
                    const unsigned int ic = __builtin_amdgcn_readlane(it, l);
                    rank += (kc > kj) || (kc == kj && ic < ijx);
                }
            }
            if (active && rank < K) {                  // bijective: all K written
                const int col = (K - 1) - rank;
                new_out[(size_t)row * K + col] = unflip32(kj);
                if ((int)cidx[j] == label) { s_has = 1; s_lab = col; }
            }
        }
        __syncthreads();
    }

    if (tid == 0) {
        int lab = s_lab;
        if (!s_has) {                        // label missed top-K: replace col 0
            new_out[(size_t)row * K] = rp[label];
            lab = 0;
        }
        new_lab[row] = (float)lab;
    }
}

extern "C" void kernel_launch(void* const* d_in, const int* in_sizes, int n_in,
                              void* d_out, int out_size, void* d_ws, size_t ws_size,
                              hipStream_t stream) {
    const float* out_mat = (const float*)d_in[0];
    const int*   labels  = (const int*)d_in[1];
    float* new_out = (float*)d_out;                      // 8192*100 floats
    float* new_lab = (float*)d_out + (size_t)NROWS * K;  // 8192 floats

    logit_selector_kernel<<<dim3(NROWS), dim3(BLK), 0, stream>>>(
        out_mat, labels, new_out, new_lab);
}